// Round 1
// baseline (247.250 us; speedup 1.0000x reference)
//
#include <hip/hip_runtime.h>
#include <math.h>

#define KB 512
#define KT 2048
#define KS 16
#define KPD 4
#define KTT 128
#define KNT (KT / KTT)
#define SROW (KS + 1)

__device__ __forceinline__ float softplus_f(float x) {
    // matches jax.nn.softplus: max(x,0) + log1p(exp(-|x|))
    return fmaxf(x, 0.0f) + log1pf(expf(-fabsf(x)));
}

__device__ __forceinline__ void mlp16(const float4 pv,
    const float* __restrict__ W1, const float* __restrict__ b1,
    const float* __restrict__ W2, const float* __restrict__ b2,
    float* __restrict__ acc)
{
#pragma unroll
    for (int j = 0; j < KS; ++j) acc[j] = b2[j];
#pragma unroll 8
    for (int k = 0; k < 64; ++k) {
        float hk = b1[k];
        hk = fmaf(pv.x, W1[k],       hk);
        hk = fmaf(pv.y, W1[64 + k],  hk);
        hk = fmaf(pv.z, W1[128 + k], hk);
        hk = fmaf(pv.w, W1[192 + k], hk);
        hk = fmaxf(hk, 0.0f);
#pragma unroll
        for (int j = 0; j < KS; ++j) acc[j] = fmaf(hk, W2[k * KS + j], acc[j]);
    }
}

__global__ __launch_bounds__(320, 2) void kalman_fused(
    const float* __restrict__ z, const float* __restrict__ p,
    const float* __restrict__ mu0, const float* __restrict__ P0,
    const float* __restrict__ Wq1, const float* __restrict__ bq1,
    const float* __restrict__ Wq2, const float* __restrict__ bq2,
    const float* __restrict__ Wr1, const float* __restrict__ br1,
    const float* __restrict__ Wr2, const float* __restrict__ br2,
    const float* __restrict__ Wg1, const float* __restrict__ bg1,
    const float* __restrict__ Wg2, const float* __restrict__ bg2,
    float* __restrict__ out)
{
    __shared__ float sQ[2][KTT][SROW];
    __shared__ float sR[2][KTT][SROW];
    __shared__ float sZ[2][KTT][KS];
    __shared__ float sG[2][KTT];

    const int b = blockIdx.x;
    const int tid = threadIdx.x;
    const float* __restrict__ zb = z + (size_t)b * KT * KS;
    const float* __restrict__ pb = p + (size_t)b * KT * KPD;
    float* __restrict__ outb = out + (size_t)b * KT * KS;

    const bool is_mlp = (tid < 256);

    auto do_mlp_tile = [&](int tile, int buf) {
        const int tt = tid & (KTT - 1);
        const int t = tile * KTT + tt;
        const float4 pv = *reinterpret_cast<const float4*>(pb + (size_t)t * KPD);
        float acc[KS];
        if (tid < KTT) {
            // q-branch (waves 0-1): wave-uniform pointers -> scalar weight loads
            mlp16(pv, Wq1, bq1, Wq2, bq2, acc);
#pragma unroll
            for (int j = 0; j < KS; ++j)
                sQ[buf][tt][j] = softplus_f(acc[j]) + 1e-8f;
            // gamma MLP (adds 160 MACs to q threads)
            float ag = bg2[0];
#pragma unroll 8
            for (int k = 0; k < 32; ++k) {
                float hk = bg1[k];
                hk = fmaf(pv.x, Wg1[k],      hk);
                hk = fmaf(pv.y, Wg1[32 + k], hk);
                hk = fmaf(pv.z, Wg1[64 + k], hk);
                hk = fmaf(pv.w, Wg1[96 + k], hk);
                hk = fmaxf(hk, 0.0f);
                ag = fmaf(hk, Wg2[k], ag);
            }
            sG[buf][tt] = 1.0f / (1.0f + expf(-ag));
        } else {
            // r-branch (waves 2-3)
            mlp16(pv, Wr1, br1, Wr2, br2, acc);
#pragma unroll
            for (int j = 0; j < KS; ++j)
                sR[buf][tt][j] = softplus_f(acc[j]) + 1e-8f;
        }
        // stage z tile (coalesced float4, 2 per thread)
        const float4* __restrict__ zt =
            reinterpret_cast<const float4*>(zb + (size_t)tile * KTT * KS);
        float4* __restrict__ zd = reinterpret_cast<float4*>(&sZ[buf][0][0]);
        zd[tid] = zt[tid];
        zd[tid + 256] = zt[tid + 256];
    };

    float mu = 0.0f, Pv = 0.0f;
    if (!is_mlp) {
        const int lane = tid - 256;
        if (lane < KS) {
            mu = mu0[(size_t)b * KS + lane];
            Pv = P0[(size_t)b * KS + lane];
        }
    }

    // prologue: tile 0 into buffer 0
    if (is_mlp) do_mlp_tile(0, 0);
    __syncthreads();

    for (int k = 0; k < KNT; ++k) {
        const int cur = k & 1;
        if (is_mlp) {
            if (k + 1 < KNT) do_mlp_tile(k + 1, cur ^ 1);
        } else {
            const int lane = tid - 256;
            if (lane < KS) {
                const int s = lane;
                constexpr int U = 4;
                float Qc[U], Rc[U], Zc[U], Gc[U];
#pragma unroll
                for (int u = 0; u < U; ++u) {
                    Qc[u] = sQ[cur][u][s];
                    Rc[u] = sR[cur][u][s];
                    Zc[u] = sZ[cur][u][s];
                    Gc[u] = sG[cur][u];
                }
                for (int tt = 0; tt < KTT; tt += U) {
                    float Qn[U], Rn[U], Zn[U], Gn[U];
                    const bool more = (tt + U < KTT);
                    if (more) {
#pragma unroll
                        for (int u = 0; u < U; ++u) {
                            Qn[u] = sQ[cur][tt + U + u][s];
                            Rn[u] = sR[cur][tt + U + u][s];
                            Zn[u] = sZ[cur][tt + U + u][s];
                            Gn[u] = sG[cur][tt + U + u];
                        }
                    }
#pragma unroll
                    for (int u = 0; u < U; ++u) {
                        const float Ppred = Pv + Qc[u];
                        float Kk = Ppred * __builtin_amdgcn_rcpf(Ppred + Rc[u]);
                        Kk = fminf(fmaxf(Kk, 1e-6f), 0.95f);
                        mu = fmaf(Gc[u] * Kk, Zc[u] - mu, mu);
                        Pv = (1.0f - Kk) * Ppred;
                        outb[(size_t)(k * KTT + tt + u) * KS + s] = mu;
                    }
                    if (more) {
#pragma unroll
                        for (int u = 0; u < U; ++u) {
                            Qc[u] = Qn[u]; Rc[u] = Rn[u];
                            Zc[u] = Zn[u]; Gc[u] = Gn[u];
                        }
                    }
                }
            }
        }
        __syncthreads();
    }
}

extern "C" void kernel_launch(void* const* d_in, const int* in_sizes, int n_in,
                              void* d_out, int out_size, void* d_ws, size_t ws_size,
                              hipStream_t stream) {
    const float* z   = (const float*)d_in[0];
    const float* p   = (const float*)d_in[1];
    const float* mu0 = (const float*)d_in[2];
    const float* P0  = (const float*)d_in[3];
    const float* Wq1 = (const float*)d_in[4];
    const float* bq1 = (const float*)d_in[5];
    const float* Wq2 = (const float*)d_in[6];
    const float* bq2 = (const float*)d_in[7];
    const float* Wr1 = (const float*)d_in[8];
    const float* br1 = (const float*)d_in[9];
    const float* Wr2 = (const float*)d_in[10];
    const float* br2 = (const float*)d_in[11];
    const float* Wg1 = (const float*)d_in[12];
    const float* bg1 = (const float*)d_in[13];
    const float* Wg2 = (const float*)d_in[14];
    const float* bg2 = (const float*)d_in[15];
    float* out = (float*)d_out;

    dim3 grid(KB), block(320);
    hipLaunchKernelGGL(kalman_fused, grid, block, 0, stream,
                       z, p, mu0, P0, Wq1, bq1, Wq2, bq2,
                       Wr1, br1, Wr2, br2, Wg1, bg1, Wg2, bg2, out);
}

// Round 2
// 175.260 us; speedup vs baseline: 1.4108x; 1.4108x over previous
//
#include <hip/hip_runtime.h>
#include <math.h>

#define KB 512
#define KT 2048
#define KS 16
#define KPD 4
#define KTT 128
#define KNT (KT / KTT)
#define SROW (KS + 1)

// Fast softplus: max(x,0) + log1p(exp(-|x|)) with hardware exp/log.
// |error| ~1e-7 relative; threshold is 4.4e-2 so this is free accuracy-wise.
__device__ __forceinline__ float softplus_f(float x) {
    float ax = fabsf(x);
    float e  = __expf(-ax);              // v_exp_f32
    return fmaxf(x, 0.0f) + __logf(1.0f + e);  // v_log_f32
}

__device__ __forceinline__ float sigmoid_f(float x) {
    return __builtin_amdgcn_rcpf(1.0f + __expf(-x));
}

__device__ __forceinline__ void mlp16(const float4 pv,
    const float* __restrict__ W1, const float* __restrict__ b1,
    const float* __restrict__ W2, const float* __restrict__ b2,
    float* __restrict__ acc)
{
#pragma unroll
    for (int j = 0; j < KS; ++j) acc[j] = b2[j];
#pragma unroll 8
    for (int k = 0; k < 64; ++k) {
        float hk = b1[k];
        hk = fmaf(pv.x, W1[k],       hk);
        hk = fmaf(pv.y, W1[64 + k],  hk);
        hk = fmaf(pv.z, W1[128 + k], hk);
        hk = fmaf(pv.w, W1[192 + k], hk);
        hk = fmaxf(hk, 0.0f);
#pragma unroll
        for (int j = 0; j < KS; ++j) acc[j] = fmaf(hk, W2[k * KS + j], acc[j]);
    }
}

__global__ __launch_bounds__(320, 2) void kalman_fused(
    const float* __restrict__ z, const float* __restrict__ p,
    const float* __restrict__ mu0, const float* __restrict__ P0,
    const float* __restrict__ Wq1, const float* __restrict__ bq1,
    const float* __restrict__ Wq2, const float* __restrict__ bq2,
    const float* __restrict__ Wr1, const float* __restrict__ br1,
    const float* __restrict__ Wr2, const float* __restrict__ br2,
    const float* __restrict__ Wg1, const float* __restrict__ bg1,
    const float* __restrict__ Wg2, const float* __restrict__ bg2,
    float* __restrict__ out)
{
    __shared__ float sQ[2][KTT][SROW];
    __shared__ float sR[2][KTT][SROW];
    __shared__ float sZ[2][KTT][KS];
    __shared__ float sG[2][KTT];

    const int b = blockIdx.x;
    const int tid = threadIdx.x;
    const float* __restrict__ zb = z + (size_t)b * KT * KS;
    const float* __restrict__ pb = p + (size_t)b * KT * KPD;
    float* __restrict__ outb = out + (size_t)b * KT * KS;

    const bool is_mlp = (tid < 256);

    auto do_mlp_tile = [&](int tile, int buf) {
        const int tt = tid & (KTT - 1);
        const int t = tile * KTT + tt;
        const float4 pv = *reinterpret_cast<const float4*>(pb + (size_t)t * KPD);
        float acc[KS];
        if (tid < KTT) {
            // q-branch (waves 0-1): wave-uniform weight pointers -> s_load
            mlp16(pv, Wq1, bq1, Wq2, bq2, acc);
#pragma unroll
            for (int j = 0; j < KS; ++j)
                sQ[buf][tt][j] = softplus_f(acc[j]) + 1e-8f;
            // gamma MLP (adds ~200 MACs to q threads)
            float ag = bg2[0];
#pragma unroll 8
            for (int k = 0; k < 32; ++k) {
                float hk = bg1[k];
                hk = fmaf(pv.x, Wg1[k],      hk);
                hk = fmaf(pv.y, Wg1[32 + k], hk);
                hk = fmaf(pv.z, Wg1[64 + k], hk);
                hk = fmaf(pv.w, Wg1[96 + k], hk);
                hk = fmaxf(hk, 0.0f);
                ag = fmaf(hk, Wg2[k], ag);
            }
            sG[buf][tt] = sigmoid_f(ag);
        } else {
            // r-branch (waves 2-3)
            mlp16(pv, Wr1, br1, Wr2, br2, acc);
#pragma unroll
            for (int j = 0; j < KS; ++j)
                sR[buf][tt][j] = softplus_f(acc[j]) + 1e-8f;
        }
        // stage z tile (coalesced float4, 2 per thread)
        const float4* __restrict__ zt =
            reinterpret_cast<const float4*>(zb + (size_t)tile * KTT * KS);
        float4* __restrict__ zd = reinterpret_cast<float4*>(&sZ[buf][0][0]);
        zd[tid] = zt[tid];
        zd[tid + 256] = zt[tid + 256];
    };

    float mu = 0.0f, Pv = 0.0f;
    if (!is_mlp) {
        const int lane = tid - 256;
        if (lane < KS) {
            mu = mu0[(size_t)b * KS + lane];
            Pv = P0[(size_t)b * KS + lane];
        }
    }

    // prologue: tile 0 into buffer 0
    if (is_mlp) do_mlp_tile(0, 0);
    __syncthreads();

    for (int k = 0; k < KNT; ++k) {
        const int cur = k & 1;
        if (is_mlp) {
            if (k + 1 < KNT) do_mlp_tile(k + 1, cur ^ 1);
        } else {
            const int lane = tid - 256;
            if (lane < KS) {
                const int s = lane;
                constexpr int U = 4;
                float Qc[U], Rc[U], Zc[U], Gc[U];
#pragma unroll
                for (int u = 0; u < U; ++u) {
                    Qc[u] = sQ[cur][u][s];
                    Rc[u] = sR[cur][u][s];
                    Zc[u] = sZ[cur][u][s];
                    Gc[u] = sG[cur][u];
                }
                for (int tt = 0; tt < KTT; tt += U) {
                    float Qn[U], Rn[U], Zn[U], Gn[U];
                    const bool more = (tt + U < KTT);
                    if (more) {
#pragma unroll
                        for (int u = 0; u < U; ++u) {
                            Qn[u] = sQ[cur][tt + U + u][s];
                            Rn[u] = sR[cur][tt + U + u][s];
                            Zn[u] = sZ[cur][tt + U + u][s];
                            Gn[u] = sG[cur][tt + U + u];
                        }
                    }
#pragma unroll
                    for (int u = 0; u < U; ++u) {
                        const float Ppred = Pv + Qc[u];
                        float Kk = Ppred * __builtin_amdgcn_rcpf(Ppred + Rc[u]);
                        Kk = fminf(fmaxf(Kk, 1e-6f), 0.95f);
                        mu = fmaf(Gc[u] * Kk, Zc[u] - mu, mu);
                        Pv = fmaf(-Kk, Ppred, Ppred);  // (1-K)*Ppred, one fma
                        outb[(size_t)(k * KTT + tt + u) * KS + s] = mu;
                    }
                    if (more) {
#pragma unroll
                        for (int u = 0; u < U; ++u) {
                            Qc[u] = Qn[u]; Rc[u] = Rn[u];
                            Zc[u] = Zn[u]; Gc[u] = Gn[u];
                        }
                    }
                }
            }
        }
        __syncthreads();
    }
}

extern "C" void kernel_launch(void* const* d_in, const int* in_sizes, int n_in,
                              void* d_out, int out_size, void* d_ws, size_t ws_size,
                              hipStream_t stream) {
    const float* z   = (const float*)d_in[0];
    const float* p   = (const float*)d_in[1];
    const float* mu0 = (const float*)d_in[2];
    const float* P0  = (const float*)d_in[3];
    const float* Wq1 = (const float*)d_in[4];
    const float* bq1 = (const float*)d_in[5];
    const float* Wq2 = (const float*)d_in[6];
    const float* bq2 = (const float*)d_in[7];
    const float* Wr1 = (const float*)d_in[8];
    const float* br1 = (const float*)d_in[9];
    const float* Wr2 = (const float*)d_in[10];
    const float* br2 = (const float*)d_in[11];
    const float* Wg1 = (const float*)d_in[12];
    const float* bg1 = (const float*)d_in[13];
    const float* Wg2 = (const float*)d_in[14];
    const float* bg2 = (const float*)d_in[15];
    float* out = (float*)d_out;

    dim3 grid(KB), block(320);
    hipLaunchKernelGGL(kalman_fused, grid, block, 0, stream,
                       z, p, mu0, P0, Wq1, bq1, Wq2, bq2,
                       Wr1, br1, Wr2, br2, Wg1, bg1, Wg2, bg2, out);
}